// Round 4
// baseline (2153.544 us; speedup 1.0000x reference)
//
#include <hip/hip_runtime.h>
#include <hip/hip_bf16.h>
#include <stdint.h>

typedef __hip_bfloat16 bf16;
typedef __bf16 bf16x8 __attribute__((ext_vector_type(8)));
typedef float f32x4 __attribute__((ext_vector_type(4)));

#define B_ 2
#define T_ 2048
#define HID_ 2048
#define H_ 16
#define D_ 128
#define QC_ 512
#define WIN_ 512
#define G_ 4
#define INTER_ 2048
#define NROW 4096  // B*T

// =================== fp32 -> bf16 conversion, 4 elems/thread ===================
__global__ __launch_bounds__(256) void cvt4(
    const float* __restrict__ in, bf16* __restrict__ out, int n4)
{
  const int i = blockIdx.x * 256 + threadIdx.x;
  if (i >= n4) return;
  const float4 v = ((const float4*)in)[i];
  bf16* p = out + (size_t)i * 4;
  p[0] = __float2bfloat16(v.x);
  p[1] = __float2bfloat16(v.y);
  p[2] = __float2bfloat16(v.z);
  p[3] = __float2bfloat16(v.w);
}

// =================== bf16 GEMM: C[M,N] = A[M,K] * B[K,N] (B native row-major) ===================
// 128x128 tile, BK=64, 4 waves each own a 64x64 quadrant (4x4 16x16x32 MFMA tiles).
// A staged [m][k]; B staged transposed into LDS [n][k], padded stride 72.
template <bool F32OUT>
__global__ __launch_bounds__(256) void gemm_bn(
    const bf16* __restrict__ Ab, const bf16* __restrict__ Bb, void* __restrict__ Cb,
    int K, int lda, int ldb, int ldc,
    long long sAz, long long sBz, long long sCz)
{
  const bf16* A = Ab + (size_t)blockIdx.z * sAz;
  const bf16* B = Bb + (size_t)blockIdx.z * sBz;
  __shared__ __align__(16) __bf16 sa[128*64];   // [m][k]
  __shared__ __align__(16) __bf16 sb[128*72];   // [n][k] padded
  const int bm = blockIdx.x * 128, bn = blockIdx.y * 128;
  const int t = threadIdx.x;
  const int wave = t >> 6, lane = t & 63;
  const int fm = lane & 15, quad = lane >> 4;
  const int wm = (wave & 1) * 64, wn = (wave >> 1) * 64;
  const int arow0 = t >> 3, acol = (t & 7) * 8;    // A staging: 32 rows x 8 chunks of 8
  const int bk0 = t >> 4, bn0 = (t & 15) * 8;      // B staging: 16 k-rows x 16 n-chunks of 8

  f32x4 acc[4][4];
#pragma unroll
  for (int i = 0; i < 4; ++i)
#pragma unroll
    for (int j = 0; j < 4; ++j) acc[i][j] = {0.f, 0.f, 0.f, 0.f};

  for (int k0 = 0; k0 < K; k0 += 64) {
    bf16x8 a4[4], b4[4];
#pragma unroll
    for (int i = 0; i < 4; ++i) {
      a4[i] = *(const bf16x8*)&A[(size_t)(bm + arow0 + i*32)*lda + k0 + acol];
      b4[i] = *(const bf16x8*)&B[(size_t)(k0 + bk0 + i*16)*ldb + bn + bn0];
    }
    __syncthreads();   // previous iter's LDS reads done
#pragma unroll
    for (int i = 0; i < 4; ++i) {
      *(bf16x8*)&sa[(arow0 + i*32)*64 + acol] = a4[i];
#pragma unroll
      for (int j = 0; j < 8; ++j)
        sb[(bn0 + j)*72 + bk0 + i*16] = b4[i][j];   // transposed write
    }
    __syncthreads();
#pragma unroll
    for (int ks = 0; ks < 64; ks += 32) {
      bf16x8 av[4], bv[4];
#pragma unroll
      for (int mt = 0; mt < 4; ++mt) av[mt] = *(const bf16x8*)&sa[(wm + mt*16 + fm)*64 + ks + quad*8];
#pragma unroll
      for (int nt = 0; nt < 4; ++nt) bv[nt] = *(const bf16x8*)&sb[(wn + nt*16 + fm)*72 + ks + quad*8];
#pragma unroll
      for (int mt = 0; mt < 4; ++mt)
#pragma unroll
        for (int nt = 0; nt < 4; ++nt)
          acc[mt][nt] = __builtin_amdgcn_mfma_f32_16x16x32_bf16(av[mt], bv[nt], acc[mt][nt], 0, 0, 0);
    }
  }
  if constexpr (F32OUT) {
    float* C = (float*)Cb + (size_t)blockIdx.z * sCz;
#pragma unroll
    for (int mt = 0; mt < 4; ++mt)
#pragma unroll
      for (int r = 0; r < 4; ++r) {
        const int row = bm + wm + mt*16 + quad*4 + r;
#pragma unroll
        for (int nt = 0; nt < 4; ++nt)
          C[(size_t)row*ldc + bn + wn + nt*16 + fm] = acc[mt][nt][r];
      }
  } else {
    bf16* C = (bf16*)Cb + (size_t)blockIdx.z * sCz;
#pragma unroll
    for (int mt = 0; mt < 4; ++mt)
#pragma unroll
      for (int r = 0; r < 4; ++r) {
        const int row = bm + wm + mt*16 + quad*4 + r;
#pragma unroll
        for (int nt = 0; nt < 4; ++nt)
          C[(size_t)row*ldc + bn + wn + nt*16 + fm] = __float2bfloat16(acc[mt][nt][r]);
      }
  }
}

// =================== fused partial-RoPE + RMSNorm, one wave per 128-elem row ===================
// lane l holds elems d=l and d=l+64. RoPE pairs (i, i+32) for i<32; dims 64..127 pass through.
// Rotation preserves sum of squares -> RMS computed from pre-rope values.
__global__ __launch_bounds__(256) void rope_rms_kernel(
    const bf16* __restrict__ in, bf16* __restrict__ out, const float* __restrict__ w,
    int in_stride, int out_stride, int t_shift)
{
  const int rid = blockIdx.x*4 + (threadIdx.x >> 6);
  const int lane = threadIdx.x & 63;
  const bf16* row = in + (size_t)rid * in_stride;
  float e0 = __bfloat162float(row[lane]);
  float e1 = __bfloat162float(row[lane + 64]);
  float s2 = e0*e0 + e1*e1;
#pragma unroll
  for (int off = 32; off; off >>= 1) s2 += __shfl_xor(s2, off);
  const float rms = rsqrtf(s2 * (1.f/128.f) + 1e-6f);
  const int tpos = (rid >> t_shift) & (T_ - 1);
  const int i = lane & 31;
  const float inv = expf(-(float)i * 0.28782313662425574f);  // ln(10000)/32
  const float ang = (float)tpos * inv;
  float sn, c;
  sincosf(ang, &sn, &c);
  const float other = __shfl_xor(e0, 32);
  const float r0 = (lane < 32) ? (e0*c - other*sn) : (other*sn + e0*c);
  bf16* orow = out + (size_t)rid * out_stride;
  orow[lane]      = __float2bfloat16(r0 * rms * w[lane]);
  orow[lane + 64] = __float2bfloat16(e1 * rms * w[lane + 64]);
}

// =================== sliding-window flash attention with sink (MQA) ===================
// grid: (T/64, H, B), 256 threads. Each wave owns 16 q-rows.
// V is read from the kv buffer ([B,T,256], v at cols 128..255) and staged transposed.
__global__ __launch_bounds__(256) void attn_kernel(
    const bf16* __restrict__ q,     // [B,T,H*D]  (post rope+rmsnorm)
    const bf16* __restrict__ k,     // [B,T,D]
    const bf16* __restrict__ kv,    // [B,T,256], v = cols 128..255
    const float* __restrict__ sink, // [H]
    bf16* __restrict__ o)           // [B,T,H*D]
{
  __shared__ __align__(16) __bf16 sQ[64*128];
  __shared__ __align__(16) __bf16 sK[64*128];
  __shared__ __align__(16) __bf16 sV[128*72];   // [d][s] padded
  __shared__ __align__(16) __bf16 sP[64*72];    // [qrow][s] padded
  const int qt = blockIdx.x, h = blockIdx.y, b = blockIdx.z;
  const int qb = qt * 64;
  const int t = threadIdx.x, wave = t >> 6, lane = t & 63;
  const int fm = lane & 15, quad = lane >> 4;
  const int vk0 = t >> 4, vd0 = (t & 15) * 8;   // V staging: 16 s-rows x 16 d-chunks of 8

  // stage Q once: 64 rows x 128 cols
#pragma unroll
  for (int i = 0; i < 4; ++i) {
    int chunk = i*256 + t;
    int r = chunk >> 4, c = (chunk & 15) * 8;
    bf16x8 v = *(const bf16x8*)&q[(size_t)((b*T_ + qb + r)*H_ + h)*D_ + c];
    *(bf16x8*)&sQ[r*128 + c] = v;
  }
  float m_run[4], l_run[4];
  const float sv = sink[h];
#pragma unroll
  for (int r = 0; r < 4; ++r) { m_run[r] = sv; l_run[r] = 1.f; }  // sink = one extra score
  f32x4 oacc[8];
#pragma unroll
  for (int i = 0; i < 8; ++i) oacc[i] = {0.f, 0.f, 0.f, 0.f};

  int lo = qb - (WIN_ - 1); if (lo < 0) lo = 0;
  const float scale = 0.08838834764831845f;  // 1/sqrt(128)
  for (int kt = lo >> 6; kt <= qt; ++kt) {
    const int kb = kt * 64;
    bf16x8 kv4[4], vv4[4];
#pragma unroll
    for (int i = 0; i < 4; ++i) {
      int chunk = i*256 + t;
      int r = chunk >> 4, c = (chunk & 15) * 8;
      kv4[i] = *(const bf16x8*)&k[(size_t)(b*T_ + kb + r)*D_ + c];
      vv4[i] = *(const bf16x8*)&kv[(size_t)(b*T_ + kb + vk0 + i*16)*256 + 128 + vd0];
    }
    __syncthreads();   // prev iter LDS reads done (iter0: sQ stores ordered too)
#pragma unroll
    for (int i = 0; i < 4; ++i) {
      int chunk = i*256 + t;
      int r = chunk >> 4, c = (chunk & 15) * 8;
      *(bf16x8*)&sK[r*128 + c] = kv4[i];
#pragma unroll
      for (int j = 0; j < 8; ++j)
        sV[(vd0 + j)*72 + vk0 + i*16] = vv4[i][j];   // transposed: sV[d][s]
    }
    __syncthreads();

    // S strip (16 q-rows x 64 k-cols per wave) = Q K^T
    f32x4 s[4];
#pragma unroll
    for (int nt = 0; nt < 4; ++nt) s[nt] = {0.f, 0.f, 0.f, 0.f};
#pragma unroll
    for (int ds = 0; ds < 4; ++ds) {
      bf16x8 aq = *(const bf16x8*)&sQ[(wave*16 + fm)*128 + ds*32 + quad*8];
#pragma unroll
      for (int nt = 0; nt < 4; ++nt) {
        bf16x8 bk = *(const bf16x8*)&sK[(nt*16 + fm)*128 + ds*32 + quad*8];
        s[nt] = __builtin_amdgcn_mfma_f32_16x16x32_bf16(aq, bk, s[nt], 0, 0, 0);
      }
    }
    // scale + window mask + row max
    const int qi0 = qb + wave*16 + quad*4;
    float mt[4];
#pragma unroll
    for (int r = 0; r < 4; ++r) mt[r] = -1e30f;
#pragma unroll
    for (int nt = 0; nt < 4; ++nt) {
      const int ki = kb + nt*16 + fm;
#pragma unroll
      for (int r = 0; r < 4; ++r) {
        const int qi = qi0 + r;
        float v = s[nt][r] * scale;
        const bool ok = (ki <= qi) && (qi - ki < WIN_);
        v = ok ? v : -1e30f;
        s[nt][r] = v;
        mt[r] = fmaxf(mt[r], v);
      }
    }
#pragma unroll
    for (int off = 1; off < 16; off <<= 1)
#pragma unroll
      for (int r = 0; r < 4; ++r) mt[r] = fmaxf(mt[r], __shfl_xor(mt[r], off));
    float alpha[4], psum[4];
#pragma unroll
    for (int r = 0; r < 4; ++r) {
      const float mn = fmaxf(m_run[r], mt[r]);
      alpha[r] = __expf(m_run[r] - mn);
      m_run[r] = mn;
      psum[r] = 0.f;
    }
#pragma unroll
    for (int nt = 0; nt < 4; ++nt)
#pragma unroll
      for (int r = 0; r < 4; ++r) {
        const float p = __expf(s[nt][r] - m_run[r]);
        s[nt][r] = p;
        psum[r] += p;
      }
#pragma unroll
    for (int off = 1; off < 16; off <<= 1)
#pragma unroll
      for (int r = 0; r < 4; ++r) psum[r] += __shfl_xor(psum[r], off);
#pragma unroll
    for (int r = 0; r < 4; ++r) l_run[r] = l_run[r]*alpha[r] + psum[r];
#pragma unroll
    for (int i = 0; i < 8; ++i)
#pragma unroll
      for (int r = 0; r < 4; ++r) oacc[i][r] *= alpha[r];
    // P: C-layout -> LDS -> A-operand layout (per-wave strip, same-wave RAW only)
#pragma unroll
    for (int nt = 0; nt < 4; ++nt)
#pragma unroll
      for (int r = 0; r < 4; ++r)
        sP[(wave*16 + quad*4 + r)*72 + nt*16 + fm] = __float2bfloat16(s[nt][r]);
    asm volatile("s_waitcnt lgkmcnt(0)" ::: "memory");
    // O += P V
#pragma unroll
    for (int ks = 0; ks < 2; ++ks) {
      bf16x8 ap = *(const bf16x8*)&sP[(wave*16 + fm)*72 + ks*32 + quad*8];
#pragma unroll
      for (int nt = 0; nt < 8; ++nt) {
        bf16x8 bv = *(const bf16x8*)&sV[(nt*16 + fm)*72 + ks*32 + quad*8];
        oacc[nt] = __builtin_amdgcn_mfma_f32_16x16x32_bf16(ap, bv, oacc[nt], 0, 0, 0);
      }
    }
  }
#pragma unroll
  for (int r = 0; r < 4; ++r) {
    const int qi = qb + wave*16 + quad*4 + r;
    const float inv_l = 1.f / l_run[r];
#pragma unroll
    for (int nt = 0; nt < 8; ++nt) {
      const int d = nt*16 + fm;
      o[(size_t)(b*T_ + qi)*(H_*D_) + h*D_ + d] = __float2bfloat16(oacc[nt][r] * inv_l);
    }
  }
}

// =========================================================================================
extern "C" void kernel_launch(void* const* d_in, const int* in_sizes, int n_in,
                              void* d_out, int out_size, void* d_ws, size_t ws_size,
                              hipStream_t stream) {
  (void)in_sizes; (void)n_in; (void)out_size; (void)ws_size;
  // Inputs are fp32 (reference setup_inputs dtype). All heavy tensors are converted
  // to bf16 in workspace; tiny vectors (norm weights, sink) are consumed as fp32.
  const float* h       = (const float*)d_in[0];   // [2,2048,2048]
  const float* wq_comp = (const float*)d_in[1];   // [2048][512]
  const float* wq_up   = (const float*)d_in[2];   // [512][2048]
  const float* wk      = (const float*)d_in[3];   // [2048][128]
  const float* wv      = (const float*)d_in[4];   // [2048][128]
  const float* qnw     = (const float*)d_in[5];   // [128]
  const float* knw     = (const float*)d_in[6];   // [128]
  const float* sink    = (const float*)d_in[7];   // [16]
  const float* w1      = (const float*)d_in[8];   // [4][512][2048]
  const float* w2      = (const float*)d_in[9];   // [8192][2048]
  float* out = (float*)d_out;                     // [2,2048,2048] fp32
  bf16* ws   = (bf16*)d_ws;

  // ---- overlaid workspace (bf16 element offsets; peak 36M elems = 72 MB) ----
  // ph1: conversions  ph2: q gemms  ph3: kv gemms  ph4: attn  ph5: out-proj chunks
  const size_t M1 = 1048576;
  const size_t o_qr   = 0;          // [4096][2048] ph2-4
  const size_t o_x1   = 0;          // [1024][8192] ph5 (qr dead)
  const size_t o_hb   = 8*M1;       // [4096][2048] ph1-3
  const size_t o_x    = 8*M1;       // [4096][2048] ph4-5 (hb dead)
  const size_t o_qc   = 16*M1;      // [4096][512]  ph2
  const size_t o_kv   = 18*M1;      // [4096][256]  ph3-4 (k|v)
  const size_t o_krt  = 19*M1;      // [4096][128]  ph3-4
  const size_t o_wqcb = 19*M1 + 524288;  // [2048][512]  ph1-2
  const size_t o_wqub = 20*M1 + 524288;  // [512][2048]  ph1-2
  const size_t o_wkb  = 21*M1 + 524288;  // [2048][128]  ph1-3
  const size_t o_wvb  = 21*M1 + 786432;  // [2048][128]  ph1-3
  const size_t o_w2b  = 16*M1;      // [8192][2048] ph5 (qc/kv/krt/w*b all dead)
  const size_t o_w1b  = 32*M1;      // [4][512][2048] ph1-5

  const dim3 tb(256);
  // ---- ph1: fp32 -> bf16 conversions ----
  cvt4<<<dim3(8192), tb, 0, stream>>>(h,       ws+o_hb,   2097152);
  cvt4<<<dim3(1024), tb, 0, stream>>>(wq_comp, ws+o_wqcb, 262144);
  cvt4<<<dim3(1024), tb, 0, stream>>>(wq_up,   ws+o_wqub, 262144);
  cvt4<<<dim3(256),  tb, 0, stream>>>(wk,      ws+o_wkb,  65536);
  cvt4<<<dim3(256),  tb, 0, stream>>>(wv,      ws+o_wvb,  65536);
  cvt4<<<dim3(4096), tb, 0, stream>>>(w1,      ws+o_w1b,  1048576);

  // ---- ph2: qc = h @ wq_comp ; q = qc @ wq_up ; rope+rms (in place) ----
  gemm_bn<false><<<dim3(32, 4, 1),  tb, 0, stream>>>(ws+o_hb, ws+o_wqcb, ws+o_qc, 2048, 2048, 512, 512, 0, 0, 0);
  gemm_bn<false><<<dim3(32, 16, 1), tb, 0, stream>>>(ws+o_qc, ws+o_wqub, ws+o_qr, 512, 512, 2048, 2048, 0, 0, 0);
  rope_rms_kernel<<<dim3(65536/4), tb, 0, stream>>>(ws+o_qr, ws+o_qr, qnw, 128, 128, 4);

  // ---- ph3: k = h @ wk, v = h @ wv (into [4096][256]); rope+rms k ----
  gemm_bn<false><<<dim3(32, 1, 1), tb, 0, stream>>>(ws+o_hb, ws+o_wkb, ws+o_kv,       2048, 2048, 128, 256, 0, 0, 0);
  gemm_bn<false><<<dim3(32, 1, 1), tb, 0, stream>>>(ws+o_hb, ws+o_wvb, ws+o_kv + 128, 2048, 2048, 128, 256, 0, 0, 0);
  rope_rms_kernel<<<dim3(4096/4), tb, 0, stream>>>(ws+o_kv, ws+o_krt, knw, 256, 128, 0);

  // ---- ph4: attention ----
  attn_kernel<<<dim3(T_/64, H_, B_), tb, 0, stream>>>(ws+o_qr, ws+o_krt, ws+o_kv, sink, ws+o_x);

  // ---- ph5: convert w2 (regions now dead), then out-proj in 4 row-chunks of 1024 ----
  cvt4<<<dim3(16384), tb, 0, stream>>>(w2, ws+o_w2b, 4194304);
  for (int c = 0; c < 4; ++c) {
    const size_t r0 = (size_t)c * 1024;
    gemm_bn<false><<<dim3(8, 16, 4), tb, 0, stream>>>(ws+o_x + r0*2048, ws+o_w1b, ws+o_x1,
                                                      512, 2048, 2048, 8192,
                                                      512, (long long)512*2048, 2048);
    gemm_bn<true><<<dim3(8, 16, 1), tb, 0, stream>>>(ws+o_x1, ws+o_w2b, out + r0*2048,
                                                     8192, 8192, 2048, 2048, 0, 0, 0);
  }
}

// Round 5
// 476.238 us; speedup vs baseline: 4.5220x; 4.5220x over previous
//
#include <hip/hip_runtime.h>
#include <hip/hip_bf16.h>
#include <stdint.h>

typedef __hip_bfloat16 bf16;
typedef __bf16 bf16x8 __attribute__((ext_vector_type(8)));
typedef float f32x4 __attribute__((ext_vector_type(4)));

#define B_ 2
#define T_ 2048
#define HID_ 2048
#define H_ 16
#define D_ 128
#define WIN_ 512

// ---- async global->LDS, 16B per lane (lds dest = wave-uniform base + lane*16) ----
__device__ __forceinline__ void async_copy16(const void* g, void* l) {
  __builtin_amdgcn_global_load_lds(
      (__attribute__((address_space(1))) void*)(uintptr_t)g,
      (__attribute__((address_space(3))) void*)(uint32_t)(uintptr_t)l,
      16, 0, 0);
}

// =================== fp32 -> bf16 conversion, 4 elems/thread ===================
__global__ __launch_bounds__(256) void cvt4(
    const float* __restrict__ in, bf16* __restrict__ out, int n4)
{
  const int i = blockIdx.x * 256 + threadIdx.x;
  if (i >= n4) return;
  const float4 v = ((const float4*)in)[i];
  bf16* p = out + (size_t)i * 4;
  p[0] = __float2bfloat16(v.x);
  p[1] = __float2bfloat16(v.y);
  p[2] = __float2bfloat16(v.z);
  p[3] = __float2bfloat16(v.w);
}

// =================== fused fp32->bf16 + transpose: out[C][R] = bf16(in[R][C]^T) ===================
// R, C multiples of 32 (all weight dims are).
__global__ __launch_bounds__(256) void cvtT(
    const float* __restrict__ in, bf16* __restrict__ out, int R, int C)
{
  __shared__ bf16 tile[32][33];
  const int bx = blockIdx.x*32, by = blockIdx.y*32;   // bx: col, by: row
  const int tx = threadIdx.x & 31, ty = threadIdx.x >> 5;
#pragma unroll
  for (int i = 0; i < 32; i += 8)
    tile[ty+i][tx] = __float2bfloat16(in[(size_t)(by + ty + i)*C + bx + tx]);
  __syncthreads();
#pragma unroll
  for (int i = 0; i < 32; i += 8)
    out[(size_t)(bx + ty + i)*R + by + tx] = tile[tx][ty+i];
}

// =================== bf16 transpose: out[C][R] = in[R][C]^T (batched via z) ===================
__global__ __launch_bounds__(256) void transpose_k(
    const bf16* __restrict__ in, bf16* __restrict__ out,
    int R, int C, int ldin, int ldout, long long inBatch, long long outBatch)
{
  __shared__ bf16 tile[32][33];
  in  += (size_t)blockIdx.z * inBatch;
  out += (size_t)blockIdx.z * outBatch;
  const int bx = blockIdx.x*32, by = blockIdx.y*32;
  const int tx = threadIdx.x & 31, ty = threadIdx.x >> 5;
#pragma unroll
  for (int i = 0; i < 32; i += 8)
    tile[ty+i][tx] = in[(size_t)(by + ty + i)*ldin + bx + tx];
  __syncthreads();
#pragma unroll
  for (int i = 0; i < 32; i += 8)
    out[(size_t)(bx + ty + i)*ldout + by + tx] = tile[tx][ty+i];
}

// =================== bf16 GEMM: C[M,N] = A[M,K] * BT[N,K]^T (m97 structure) ===================
// 128x128 tile, BK=64, global_load_lds width-16 staging, 4 waves = 64x64 quadrants.
template <bool F32OUT>
__global__ __launch_bounds__(256) void gemm_bt(
    const bf16* __restrict__ Ab, const bf16* __restrict__ Bb, void* __restrict__ Cb,
    int K, int lda, int ldb, int ldc,
    long long sAz, long long sBz, long long sCz)
{
  const bf16* A = Ab + (size_t)blockIdx.z * sAz;
  const bf16* B = Bb + (size_t)blockIdx.z * sBz;
  __shared__ __align__(16) __bf16 sa[128*64];
  __shared__ __align__(16) __bf16 sb[128*64];
  const int bm = blockIdx.x * 128, bn = blockIdx.y * 128;
  const int t = threadIdx.x;
  const int wave = t >> 6, lane = t & 63;
  const int fm = lane & 15, quad = lane >> 4;
  const int wm = (wave & 1) * 64, wn = (wave >> 1) * 64;
  const int arow0 = t >> 3, acol = (t & 7) * 8;   // staging: 32 rows x 8 chunks of 8 per pass

  f32x4 acc[4][4];
#pragma unroll
  for (int i = 0; i < 4; ++i)
#pragma unroll
    for (int j = 0; j < 4; ++j) acc[i][j] = {0.f, 0.f, 0.f, 0.f};

  for (int k0 = 0; k0 < K; k0 += 64) {
    __syncthreads();   // prev iter's LDS reads complete
#pragma unroll
    for (int i = 0; i < 4; ++i)
      async_copy16(&A[(size_t)(bm + arow0 + i*32)*lda + k0 + acol], &sa[(size_t)(i*256 + wave*64)*8]);
#pragma unroll
    for (int i = 0; i < 4; ++i)
      async_copy16(&B[(size_t)(bn + arow0 + i*32)*ldb + k0 + acol], &sb[(size_t)(i*256 + wave*64)*8]);
    __syncthreads();   // drains vmcnt (async LDS writes) + barrier
#pragma unroll
    for (int ks = 0; ks < 64; ks += 32) {
      bf16x8 av[4], bv[4];
#pragma unroll
      for (int mt = 0; mt < 4; ++mt) av[mt] = *(const bf16x8*)&sa[(wm + mt*16 + fm)*64 + ks + quad*8];
#pragma unroll
      for (int nt = 0; nt < 4; ++nt) bv[nt] = *(const bf16x8*)&sb[(wn + nt*16 + fm)*64 + ks + quad*8];
#pragma unroll
      for (int mt = 0; mt < 4; ++mt)
#pragma unroll
        for (int nt = 0; nt < 4; ++nt)
          acc[mt][nt] = __builtin_amdgcn_mfma_f32_16x16x32_bf16(av[mt], bv[nt], acc[mt][nt], 0, 0, 0);
    }
  }
  if constexpr (F32OUT) {
    float* C = (float*)Cb + (size_t)blockIdx.z * sCz;
#pragma unroll
    for (int mt = 0; mt < 4; ++mt)
#pragma unroll
      for (int r = 0; r < 4; ++r) {
        const int row = bm + wm + mt*16 + quad*4 + r;
#pragma unroll
        for (int nt = 0; nt < 4; ++nt)
          C[(size_t)row*ldc + bn + wn + nt*16 + fm] = acc[mt][nt][r];
      }
  } else {
    bf16* C = (bf16*)Cb + (size_t)blockIdx.z * sCz;
#pragma unroll
    for (int mt = 0; mt < 4; ++mt)
#pragma unroll
      for (int r = 0; r < 4; ++r) {
        const int row = bm + wm + mt*16 + quad*4 + r;
#pragma unroll
        for (int nt = 0; nt < 4; ++nt)
          C[(size_t)row*ldc + bn + wn + nt*16 + fm] = __float2bfloat16(acc[mt][nt][r]);
      }
  }
}

// =================== fused partial-RoPE + RMSNorm, one wave per 128-elem row ===================
__global__ __launch_bounds__(256) void rope_rms_kernel(
    const bf16* __restrict__ in, bf16* __restrict__ out, const float* __restrict__ w,
    int in_stride, int out_stride, int t_shift)
{
  const int rid = blockIdx.x*4 + (threadIdx.x >> 6);
  const int lane = threadIdx.x & 63;
  const bf16* row = in + (size_t)rid * in_stride;
  float e0 = __bfloat162float(row[lane]);
  float e1 = __bfloat162float(row[lane + 64]);
  float s2 = e0*e0 + e1*e1;
#pragma unroll
  for (int off = 32; off; off >>= 1) s2 += __shfl_xor(s2, off);
  const float rms = rsqrtf(s2 * (1.f/128.f) + 1e-6f);
  const int tpos = (rid >> t_shift) & (T_ - 1);
  const int i = lane & 31;
  const float inv = expf(-(float)i * 0.28782313662425574f);  // ln(10000)/32
  const float ang = (float)tpos * inv;
  float sn, c;
  sincosf(ang, &sn, &c);
  const float other = __shfl_xor(e0, 32);
  const float r0 = (lane < 32) ? (e0*c - other*sn) : (other*sn + e0*c);
  bf16* orow = out + (size_t)rid * out_stride;
  orow[lane]      = __float2bfloat16(r0 * rms * w[lane]);
  orow[lane + 64] = __float2bfloat16(e1 * rms * w[lane + 64]);
}

// =================== sliding-window flash attention with sink (MQA) ===================
// grid: (T/64, H, B), 256 threads; async staging for Q/K/V (V pre-transposed [B,D,T]).
__global__ __launch_bounds__(256) void attn_kernel(
    const bf16* __restrict__ q,     // [B,T,H*D]
    const bf16* __restrict__ k,     // [B,T,D]
    const bf16* __restrict__ vt,    // [B,D,T]
    const float* __restrict__ sink, // [H]
    bf16* __restrict__ o)           // [B,T,H*D]
{
  __shared__ __align__(16) __bf16 sQ[64*128];
  __shared__ __align__(16) __bf16 sK[64*128];
  __shared__ __align__(16) __bf16 sV[128*64];   // [d][s]
  __shared__ __align__(16) __bf16 sP[64*72];    // [qrow][s] padded stride 72
  const int qt = blockIdx.x, h = blockIdx.y, b = blockIdx.z;
  const int qb = qt * 64;
  const int t = threadIdx.x, wave = t >> 6, lane = t & 63;
  const int fm = lane & 15, quad = lane >> 4;

  // stage Q once (async): 64 rows x 16 chunks of 8
#pragma unroll
  for (int i = 0; i < 4; ++i) {
    int chunk = i*256 + t;
    int r = chunk >> 4, c8 = chunk & 15;
    async_copy16(&q[(size_t)((b*T_ + qb + r)*H_ + h)*D_ + c8*8], &sQ[(size_t)(i*256 + wave*64)*8]);
  }
  float m_run[4], l_run[4];
  const float sv = sink[h];
#pragma unroll
  for (int r = 0; r < 4; ++r) { m_run[r] = sv; l_run[r] = 1.f; }
  f32x4 oacc[8];
#pragma unroll
  for (int i = 0; i < 8; ++i) oacc[i] = {0.f, 0.f, 0.f, 0.f};

  int lo = qb - (WIN_ - 1); if (lo < 0) lo = 0;
  const float scale = 0.08838834764831845f;  // 1/sqrt(128)
  for (int kt = lo >> 6; kt <= qt; ++kt) {
    const int kb = kt * 64;
    __syncthreads();   // prev iter LDS reads done
#pragma unroll
    for (int i = 0; i < 4; ++i) {   // K tile: 64 rows x 16 chunks
      int chunk = i*256 + t;
      int r = chunk >> 4, c8 = chunk & 15;
      async_copy16(&k[(size_t)(b*T_ + kb + r)*D_ + c8*8], &sK[(size_t)(i*256 + wave*64)*8]);
    }
#pragma unroll
    for (int i = 0; i < 4; ++i) {   // V^T tile: 128 d-rows x 8 chunks
      int chunk = i*256 + t;
      int d = chunk >> 3, c8 = chunk & 7;
      async_copy16(&vt[(size_t)(b*D_ + d)*T_ + kb + c8*8], &sV[(size_t)(i*256 + wave*64)*8]);
    }
    __syncthreads();   // drains vmcnt + barrier

    // S strip (16 q-rows x 64 k-cols per wave) = Q K^T
    f32x4 s[4];
#pragma unroll
    for (int nt = 0; nt < 4; ++nt) s[nt] = {0.f, 0.f, 0.f, 0.f};
#pragma unroll
    for (int ds = 0; ds < 4; ++ds) {
      bf16x8 aq = *(const bf16x8*)&sQ[(wave*16 + fm)*128 + ds*32 + quad*8];
#pragma unroll
      for (int nt = 0; nt < 4; ++nt) {
        bf16x8 bk = *(const bf16x8*)&sK[(nt*16 + fm)*128 + ds*32 + quad*8];
        s[nt] = __builtin_amdgcn_mfma_f32_16x16x32_bf16(aq, bk, s[nt], 0, 0, 0);
      }
    }
    const int qi0 = qb + wave*16 + quad*4;
    float mt[4];
#pragma unroll
    for (int r = 0; r < 4; ++r) mt[r] = -1e30f;
#pragma unroll
    for (int nt = 0; nt < 4; ++nt) {
      const int ki = kb + nt*16 + fm;
#pragma unroll
      for (int r = 0; r < 4; ++r) {
        const int qi = qi0 + r;
        float v = s[nt][r] * scale;
        const bool ok = (ki <= qi) && (qi - ki < WIN_);
        v = ok ? v : -1e30f;
        s[nt][r] = v;
        mt[r] = fmaxf(mt[r], v);
      }
    }
#pragma unroll
    for (int off = 1; off < 16; off <<= 1)
#pragma unroll
      for (int r = 0; r < 4; ++r) mt[r] = fmaxf(mt[r], __shfl_xor(mt[r], off));
    float alpha[4], psum[4];
#pragma unroll
    for (int r = 0; r < 4; ++r) {
      const float mn = fmaxf(m_run[r], mt[r]);
      alpha[r] = __expf(m_run[r] - mn);
      m_run[r] = mn;
      psum[r] = 0.f;
    }
#pragma unroll
    for (int nt = 0; nt < 4; ++nt)
#pragma unroll
      for (int r = 0; r < 4; ++r) {
        const float p = __expf(s[nt][r] - m_run[r]);
        s[nt][r] = p;
        psum[r] += p;
      }
#pragma unroll
    for (int off = 1; off < 16; off <<= 1)
#pragma unroll
      for (int r = 0; r < 4; ++r) psum[r] += __shfl_xor(psum[r], off);
#pragma unroll
    for (int r = 0; r < 4; ++r) l_run[r] = l_run[r]*alpha[r] + psum[r];
#pragma unroll
    for (int i = 0; i < 8; ++i)
#pragma unroll
      for (int r = 0; r < 4; ++r) oacc[i][r] *= alpha[r];
    // P: C-layout -> LDS -> A-operand layout (per-wave strip, same-wave RAW only)
#pragma unroll
    for (int nt = 0; nt < 4; ++nt)
#pragma unroll
      for (int r = 0; r < 4; ++r)
        sP[(wave*16 + quad*4 + r)*72 + nt*16 + fm] = __float2bfloat16(s[nt][r]);
    asm volatile("s_waitcnt lgkmcnt(0)" ::: "memory");
    // O += P V
#pragma unroll
    for (int ks = 0; ks < 2; ++ks) {
      bf16x8 ap = *(const bf16x8*)&sP[(wave*16 + fm)*72 + ks*32 + quad*8];
#pragma unroll
      for (int nt = 0; nt < 8; ++nt) {
        bf16x8 bv = *(const bf16x8*)&sV[(nt*16 + fm)*64 + ks*32 + quad*8];
        oacc[nt] = __builtin_amdgcn_mfma_f32_16x16x32_bf16(ap, bv, oacc[nt], 0, 0, 0);
      }
    }
  }
#pragma unroll
  for (int r = 0; r < 4; ++r) {
    const int qi = qb + wave*16 + quad*4 + r;
    const float inv_l = 1.f / l_run[r];
#pragma unroll
    for (int nt = 0; nt < 8; ++nt) {
      const int d = nt*16 + fm;
      o[(size_t)(b*T_ + qi)*(H_*D_) + h*D_ + d] = __float2bfloat16(oacc[nt][r] * inv_l);
    }
  }
}

// =========================================================================================
extern "C" void kernel_launch(void* const* d_in, const int* in_sizes, int n_in,
                              void* d_out, int out_size, void* d_ws, size_t ws_size,
                              hipStream_t stream) {
  (void)in_sizes; (void)n_in; (void)out_size; (void)ws_size;
  const float* h       = (const float*)d_in[0];   // [2,2048,2048]
  const float* wq_comp = (const float*)d_in[1];   // [2048][512]
  const float* wq_up   = (const float*)d_in[2];   // [512][2048]
  const float* wk      = (const float*)d_in[3];   // [2048][128]
  const float* wv      = (const float*)d_in[4];   // [2048][128]
  const float* qnw     = (const float*)d_in[5];   // [128]
  const float* knw     = (const float*)d_in[6];   // [128]
  const float* sink    = (const float*)d_in[7];   // [16]
  const float* w1      = (const float*)d_in[8];   // [4][512][2048]
  const float* w2      = (const float*)d_in[9];   // [8192][2048]
  float* out = (float*)d_out;                     // [2,2048,2048] fp32
  bf16* ws   = (bf16*)d_ws;

  // ---- overlaid workspace (bf16 element offsets; peak 35.5M elems = 71 MB) ----
  // ph1 cvt -> ph2 q-path -> ph3 kv-path -> ph4 attn -> ph5 Weff + out
  const size_t M1 = 1048576;
  const size_t o_hb   = 0;               // [4096][2048] ph1-3
  const size_t o_qr   = 8*M1;            // [4096][2048] ph2-4
  const size_t o_w2T  = 0;               // [2048][8192] ph5 (hb,qr dead)
  const size_t o_qc   = 16*M1;           // [4096][512]  ph2
  const size_t o_kv   = 16*M1;           // [4096][256]  ph3 (qc dead)
  const size_t o_WefT = 16*M1;           // [2048][2048] ph5 (kv dead)
  const size_t o_krt  = 20*M1;           // [4096][128]  ph3-4
  const size_t o_vt   = 20*M1 + 524288;  // [2][128][2048] ph3-4
  const size_t o_wqcT = 21*M1;           // [512][2048]  ph1-2
  const size_t o_wquT = 22*M1;           // [2048][512]  ph1-2
  const size_t o_wkvT = 23*M1;           // [256][2048]  ph1-3 (wkT|wvT)
  const size_t o_w1b  = 23*M1 + 524288;  // [4][512][2048] ph1-5
  const size_t o_x    = 27*M1 + 524288;  // [4096][2048] ph4-5

  const dim3 tb(256);
  // ---- ph1: conversions (+ weight transposes fused) ----
  cvt4<<<dim3(8192), tb, 0, stream>>>(h,  ws+o_hb,  2097152);
  cvt4<<<dim3(4096), tb, 0, stream>>>(w1, ws+o_w1b, 1048576);
  cvtT<<<dim3(16, 64), tb, 0, stream>>>(wq_comp, ws+o_wqcT, 2048, 512);
  cvtT<<<dim3(64, 16), tb, 0, stream>>>(wq_up,   ws+o_wquT, 512, 2048);
  cvtT<<<dim3(4, 64),  tb, 0, stream>>>(wk, ws+o_wkvT,                     2048, 128);
  cvtT<<<dim3(4, 64),  tb, 0, stream>>>(wv, ws+o_wkvT + (size_t)128*2048,  2048, 128);

  // ---- ph2: qc = h @ wq_comp ; q = qc @ wq_up ; rope+rms (in place) ----
  gemm_bt<false><<<dim3(32, 4),  tb, 0, stream>>>(ws+o_hb, ws+o_wqcT, ws+o_qc, 2048, 2048, 2048, 512, 0, 0, 0);
  gemm_bt<false><<<dim3(32, 16), tb, 0, stream>>>(ws+o_qc, ws+o_wquT, ws+o_qr, 512, 512, 512, 2048, 0, 0, 0);
  rope_rms_kernel<<<dim3(16384), tb, 0, stream>>>(ws+o_qr, ws+o_qr, qnw, 128, 128, 4);

  // ---- ph3: kv = h @ [wk|wv] ; rope+rms k -> krt ; transpose v -> vt ----
  gemm_bt<false><<<dim3(32, 2), tb, 0, stream>>>(ws+o_hb, ws+o_wkvT, ws+o_kv, 2048, 2048, 2048, 256, 0, 0, 0);
  rope_rms_kernel<<<dim3(1024), tb, 0, stream>>>(ws+o_kv, ws+o_krt, knw, 256, 128, 0);
  transpose_k<<<dim3(4, 64, 2), tb, 0, stream>>>(ws+o_kv + 128, ws+o_vt, 2048, 128, 256, 2048,
                                                 (long long)2048*256, (long long)128*2048);

  // ---- ph4: attention ----
  attn_kernel<<<dim3(T_/64, H_, B_), tb, 0, stream>>>(ws+o_qr, ws+o_krt, ws+o_vt, sink, ws+o_x);

  // ---- ph5: WeffT = w2T_g @ w1_g^T per group (z=g), then out = x @ WeffT^T ----
  cvtT<<<dim3(64, 256), tb, 0, stream>>>(w2, ws+o_w2T, 8192, 2048);
  // WeffT[o][g*512+i] = sum_j w2T[o][g*2048+j] * w1[g][i][j]
  gemm_bt<false><<<dim3(16, 4, 4), tb, 0, stream>>>(ws+o_w2T, ws+o_w1b, ws+o_WefT,
                                                    2048, 8192, 2048, 2048,
                                                    2048, (long long)512*2048, 512);
  gemm_bt<true><<<dim3(32, 16), tb, 0, stream>>>(ws+o_x, ws+o_WefT, out,
                                                 2048, 2048, 2048, 2048, 0, 0, 0);
}

// Round 6
// 461.979 us; speedup vs baseline: 4.6616x; 1.0309x over previous
//
#include <hip/hip_runtime.h>
#include <hip/hip_bf16.h>
#include <stdint.h>

typedef __hip_bfloat16 bf16;
typedef __bf16 bf16x8 __attribute__((ext_vector_type(8)));
typedef float f32x4 __attribute__((ext_vector_type(4)));

#define B_ 2
#define T_ 2048
#define HID_ 2048
#define H_ 16
#define D_ 128
#define WIN_ 512

// ---- async global->LDS, 16B per lane (lds dest = wave-uniform base + lane*16) ----
__device__ __forceinline__ void async_copy16(const void* g, void* l) {
  __builtin_amdgcn_global_load_lds(
      (__attribute__((address_space(1))) void*)(uintptr_t)g,
      (__attribute__((address_space(3))) void*)(uint32_t)(uintptr_t)l,
      16, 0, 0);
}

// =================== fp32 -> bf16 conversion, 4 elems/thread ===================
__global__ __launch_bounds__(256) void cvt4(
    const float* __restrict__ in, bf16* __restrict__ out, int n4)
{
  const int i = blockIdx.x * 256 + threadIdx.x;
  if (i >= n4) return;
  const float4 v = ((const float4*)in)[i];
  bf16* p = out + (size_t)i * 4;
  p[0] = __float2bfloat16(v.x);
  p[1] = __float2bfloat16(v.y);
  p[2] = __float2bfloat16(v.z);
  p[3] = __float2bfloat16(v.w);
}

// =================== fused fp32->bf16 + transpose: out[C][R] = bf16(in[R][C]^T) ===================
__global__ __launch_bounds__(256) void cvtT(
    const float* __restrict__ in, bf16* __restrict__ out, int R, int C)
{
  __shared__ bf16 tile[32][33];
  const int bx = blockIdx.x*32, by = blockIdx.y*32;
  const int tx = threadIdx.x & 31, ty = threadIdx.x >> 5;
#pragma unroll
  for (int i = 0; i < 32; i += 8)
    tile[ty+i][tx] = __float2bfloat16(in[(size_t)(by + ty + i)*C + bx + tx]);
  __syncthreads();
#pragma unroll
  for (int i = 0; i < 32; i += 8)
    out[(size_t)(bx + ty + i)*R + by + tx] = tile[tx][ty+i];
}

// =================== bf16 transpose: out[C][R] = in[R][C]^T (batched via z) ===================
__global__ __launch_bounds__(256) void transpose_k(
    const bf16* __restrict__ in, bf16* __restrict__ out,
    int R, int C, int ldin, int ldout, long long inBatch, long long outBatch)
{
  __shared__ bf16 tile[32][33];
  in  += (size_t)blockIdx.z * inBatch;
  out += (size_t)blockIdx.z * outBatch;
  const int bx = blockIdx.x*32, by = blockIdx.y*32;
  const int tx = threadIdx.x & 31, ty = threadIdx.x >> 5;
#pragma unroll
  for (int i = 0; i < 32; i += 8)
    tile[ty+i][tx] = in[(size_t)(by + ty + i)*ldin + bx + tx];
  __syncthreads();
#pragma unroll
  for (int i = 0; i < 32; i += 8)
    out[(size_t)(bx + ty + i)*ldout + by + tx] = tile[tx][ty+i];
}

// =================== bf16 GEMM: C[M,N] = A[M,K] * BT[N,K]^T (m97 structure) ===================
template <bool F32OUT>
__global__ __launch_bounds__(256) void gemm_bt(
    const bf16* __restrict__ Ab, const bf16* __restrict__ Bb, void* __restrict__ Cb,
    int K, int lda, int ldb, int ldc,
    long long sAz, long long sBz, long long sCz)
{
  const bf16* A = Ab + (size_t)blockIdx.z * sAz;
  const bf16* B = Bb + (size_t)blockIdx.z * sBz;
  __shared__ __align__(16) __bf16 sa[128*64];
  __shared__ __align__(16) __bf16 sb[128*64];
  const int bm = blockIdx.x * 128, bn = blockIdx.y * 128;
  const int t = threadIdx.x;
  const int wave = t >> 6, lane = t & 63;
  const int fm = lane & 15, quad = lane >> 4;
  const int wm = (wave & 1) * 64, wn = (wave >> 1) * 64;
  const int arow0 = t >> 3, acol = (t & 7) * 8;

  f32x4 acc[4][4];
#pragma unroll
  for (int i = 0; i < 4; ++i)
#pragma unroll
    for (int j = 0; j < 4; ++j) acc[i][j] = {0.f, 0.f, 0.f, 0.f};

  for (int k0 = 0; k0 < K; k0 += 64) {
    __syncthreads();
#pragma unroll
    for (int i = 0; i < 4; ++i)
      async_copy16(&A[(size_t)(bm + arow0 + i*32)*lda + k0 + acol], &sa[(size_t)(i*256 + wave*64)*8]);
#pragma unroll
    for (int i = 0; i < 4; ++i)
      async_copy16(&B[(size_t)(bn + arow0 + i*32)*ldb + k0 + acol], &sb[(size_t)(i*256 + wave*64)*8]);
    __syncthreads();
#pragma unroll
    for (int ks = 0; ks < 64; ks += 32) {
      bf16x8 av[4], bv[4];
#pragma unroll
      for (int mt = 0; mt < 4; ++mt) av[mt] = *(const bf16x8*)&sa[(wm + mt*16 + fm)*64 + ks + quad*8];
#pragma unroll
      for (int nt = 0; nt < 4; ++nt) bv[nt] = *(const bf16x8*)&sb[(wn + nt*16 + fm)*64 + ks + quad*8];
#pragma unroll
      for (int mt = 0; mt < 4; ++mt)
#pragma unroll
        for (int nt = 0; nt < 4; ++nt)
          acc[mt][nt] = __builtin_amdgcn_mfma_f32_16x16x32_bf16(av[mt], bv[nt], acc[mt][nt], 0, 0, 0);
    }
  }
  if constexpr (F32OUT) {
    float* C = (float*)Cb + (size_t)blockIdx.z * sCz;
#pragma unroll
    for (int mt = 0; mt < 4; ++mt)
#pragma unroll
      for (int r = 0; r < 4; ++r) {
        const int row = bm + wm + mt*16 + quad*4 + r;
#pragma unroll
        for (int nt = 0; nt < 4; ++nt)
          C[(size_t)row*ldc + bn + wn + nt*16 + fm] = acc[mt][nt][r];
      }
  } else {
    bf16* C = (bf16*)Cb + (size_t)blockIdx.z * sCz;
#pragma unroll
    for (int mt = 0; mt < 4; ++mt)
#pragma unroll
      for (int r = 0; r < 4; ++r) {
        const int row = bm + wm + mt*16 + quad*4 + r;
#pragma unroll
        for (int nt = 0; nt < 4; ++nt)
          C[(size_t)row*ldc + bn + wn + nt*16 + fm] = __float2bfloat16(acc[mt][nt][r]);
      }
  }
}

// =================== fused partial-RoPE + RMSNorm (+ output scale), one wave per row ===================
__global__ __launch_bounds__(256) void rope_rms_kernel(
    const bf16* __restrict__ in, bf16* __restrict__ out, const float* __restrict__ w,
    int in_stride, int out_stride, int t_shift, float oscale)
{
  const int rid = blockIdx.x*4 + (threadIdx.x >> 6);
  const int lane = threadIdx.x & 63;
  const bf16* row = in + (size_t)rid * in_stride;
  float e0 = __bfloat162float(row[lane]);
  float e1 = __bfloat162float(row[lane + 64]);
  float s2 = e0*e0 + e1*e1;
#pragma unroll
  for (int off = 32; off; off >>= 1) s2 += __shfl_xor(s2, off);
  const float rms = rsqrtf(s2 * (1.f/128.f) + 1e-6f) * oscale;
  const int tpos = (rid >> t_shift) & (T_ - 1);
  const int i = lane & 31;
  const float inv = expf(-(float)i * 0.28782313662425574f);  // ln(10000)/32
  const float ang = (float)tpos * inv;
  float sn, c;
  sincosf(ang, &sn, &c);
  const float other = __shfl_xor(e0, 32);
  const float r0 = (lane < 32) ? (e0*c - other*sn) : (other*sn + e0*c);
  bf16* orow = out + (size_t)rid * out_stride;
  orow[lane]      = __float2bfloat16(r0 * rms * w[lane]);
  orow[lane + 64] = __float2bfloat16(e1 * rms * w[lane + 64]);
}

// =================== sliding-window flash attention with sink (MQA), max-free softmax ===================
// Q is pre-scaled by 1/(sqrt(D)*ln2), so p = exp2(q.k) directly. Bound: after RMSNorm
// |q||k|/sqrt(D) <= sqrt(D) -> exp2 arg <= 16.34 -> p <= 8.3e4, l <= 4.3e7: no overflow.
__global__ __launch_bounds__(256) void attn_kernel(
    const bf16* __restrict__ q,     // [B,T,H*D]  (pre-scaled)
    const bf16* __restrict__ k,     // [B,T,D]
    const bf16* __restrict__ vt,    // [B,D,T]
    const float* __restrict__ sink, // [H]
    bf16* __restrict__ o)           // [B,T,H*D]
{
  __shared__ __align__(16) __bf16 sQ[64*128];
  __shared__ __align__(16) __bf16 sK[64*128];
  __shared__ __align__(16) __bf16 sV[128*64];   // [d][s]
  __shared__ __align__(16) __bf16 sP[64*72];    // [qrow][s] padded stride 72
  const int qt = blockIdx.x, h = blockIdx.y, b = blockIdx.z;
  const int qb = qt * 64;
  const int t = threadIdx.x, wave = t >> 6, lane = t & 63;
  const int fm = lane & 15, quad = lane >> 4;
  const int qw = qb + wave*16;   // this wave's first q row

#pragma unroll
  for (int i = 0; i < 4; ++i) {   // stage Q once (async)
    int chunk = i*256 + t;
    int r = chunk >> 4, c8 = chunk & 15;
    async_copy16(&q[(size_t)((b*T_ + qb + r)*H_ + h)*D_ + c8*8], &sQ[(size_t)(i*256 + wave*64)*8]);
  }
  float l_run[4] = {0.f, 0.f, 0.f, 0.f};   // per-lane partial denominators
  f32x4 oacc[8];
#pragma unroll
  for (int i = 0; i < 8; ++i) oacc[i] = {0.f, 0.f, 0.f, 0.f};

  int lo = qb - (WIN_ - 1); if (lo < 0) lo = 0;
  for (int kt = lo >> 6; kt <= qt; ++kt) {
    const int kb = kt * 64;
    __syncthreads();   // prev iter LDS reads done
#pragma unroll
    for (int i = 0; i < 4; ++i) {   // K tile
      int chunk = i*256 + t;
      int r = chunk >> 4, c8 = chunk & 15;
      async_copy16(&k[(size_t)(b*T_ + kb + r)*D_ + c8*8], &sK[(size_t)(i*256 + wave*64)*8]);
    }
#pragma unroll
    for (int i = 0; i < 4; ++i) {   // V^T tile
      int chunk = i*256 + t;
      int d = chunk >> 3, c8 = chunk & 7;
      async_copy16(&vt[(size_t)(b*D_ + d)*T_ + kb + c8*8], &sV[(size_t)(i*256 + wave*64)*8]);
    }
    __syncthreads();   // drains vmcnt + barrier

    // S strip (16 q-rows x 64 k-cols per wave) = Q K^T  (log2-units)
    f32x4 s[4];
#pragma unroll
    for (int nt = 0; nt < 4; ++nt) s[nt] = {0.f, 0.f, 0.f, 0.f};
#pragma unroll
    for (int ds = 0; ds < 4; ++ds) {
      bf16x8 aq = *(const bf16x8*)&sQ[(wave*16 + fm)*128 + ds*32 + quad*8];
#pragma unroll
      for (int nt = 0; nt < 4; ++nt) {
        bf16x8 bk = *(const bf16x8*)&sK[(nt*16 + fm)*128 + ds*32 + quad*8];
        s[nt] = __builtin_amdgcn_mfma_f32_16x16x32_bf16(aq, bk, s[nt], 0, 0, 0);
      }
    }
    // wave-uniform interior test: all 64 cols causal-valid and in-window for all 16 rows
    const bool interior = (kb + 63 <= qw) && (kb >= qw - (WIN_ - 16));
    if (!interior) {
      const int qi0 = qb + wave*16 + quad*4;
#pragma unroll
      for (int nt = 0; nt < 4; ++nt) {
        const int ki = kb + nt*16 + fm;
#pragma unroll
        for (int r = 0; r < 4; ++r) {
          const int qi = qi0 + r;
          const bool ok = (ki <= qi) && (qi - ki < WIN_);
          s[nt][r] = ok ? s[nt][r] : -1e30f;
        }
      }
    }
    // p = 2^s ; accumulate per-lane l partials; stage P
#pragma unroll
    for (int nt = 0; nt < 4; ++nt)
#pragma unroll
      for (int r = 0; r < 4; ++r) {
        const float p = __builtin_exp2f(s[nt][r]);
        l_run[r] += p;
        sP[(wave*16 + quad*4 + r)*72 + nt*16 + fm] = __float2bfloat16(p);
      }
    asm volatile("s_waitcnt lgkmcnt(0)" ::: "memory");
    // O += P V
#pragma unroll
    for (int ks = 0; ks < 2; ++ks) {
      bf16x8 ap = *(const bf16x8*)&sP[(wave*16 + fm)*72 + ks*32 + quad*8];
#pragma unroll
      for (int nt = 0; nt < 8; ++nt) {
        bf16x8 bv = *(const bf16x8*)&sV[(nt*16 + fm)*64 + ks*32 + quad*8];
        oacc[nt] = __builtin_amdgcn_mfma_f32_16x16x32_bf16(ap, bv, oacc[nt], 0, 0, 0);
      }
    }
  }
  // final l: reduce over the 16 fm lanes (row = quad*4+r), add sink term
#pragma unroll
  for (int off = 1; off < 16; off <<= 1)
#pragma unroll
    for (int r = 0; r < 4; ++r) l_run[r] += __shfl_xor(l_run[r], off);
  const float sink_p = __builtin_exp2f(sink[h] * 1.4426950408889634f);
#pragma unroll
  for (int r = 0; r < 4; ++r) {
    const int qi = qb + wave*16 + quad*4 + r;
    const float inv_l = 1.f / (l_run[r] + sink_p);
#pragma unroll
    for (int nt = 0; nt < 8; ++nt) {
      const int d = nt*16 + fm;
      o[(size_t)(b*T_ + qi)*(H_*D_) + h*D_ + d] = __float2bfloat16(oacc[nt][r] * inv_l);
    }
  }
}

// =========================================================================================
extern "C" void kernel_launch(void* const* d_in, const int* in_sizes, int n_in,
                              void* d_out, int out_size, void* d_ws, size_t ws_size,
                              hipStream_t stream) {
  (void)in_sizes; (void)n_in; (void)out_size; (void)ws_size;
  const float* h       = (const float*)d_in[0];
  const float* wq_comp = (const float*)d_in[1];
  const float* wq_up   = (const float*)d_in[2];
  const float* wk      = (const float*)d_in[3];
  const float* wv      = (const float*)d_in[4];
  const float* qnw     = (const float*)d_in[5];
  const float* knw     = (const float*)d_in[6];
  const float* sink    = (const float*)d_in[7];
  const float* w1      = (const float*)d_in[8];
  const float* w2      = (const float*)d_in[9];
  float* out = (float*)d_out;
  bf16* ws   = (bf16*)d_ws;

  // ---- overlaid workspace (bf16 element offsets; peak 35.5M elems = 71 MB) ----
  const size_t M1 = 1048576;
  const size_t o_hb   = 0;               // [4096][2048] ph1-3
  const size_t o_qr   = 8*M1;            // [4096][2048] ph2-4
  const size_t o_w2T  = 0;               // [2048][8192] ph5 (hb,qr dead)
  const size_t o_qc   = 16*M1;           // [4096][512]  ph2
  const size_t o_kv   = 16*M1;           // [4096][256]  ph3 (qc dead)
  const size_t o_WefT = 16*M1;           // [2048][2048] ph5 (kv dead)
  const size_t o_krt  = 20*M1;           // [4096][128]  ph3-4
  const size_t o_vt   = 20*M1 + 524288;  // [2][128][2048] ph3-4
  const size_t o_wqcT = 21*M1;           // [512][2048]  ph1-2
  const size_t o_wquT = 22*M1;           // [2048][512]  ph1-2
  const size_t o_wkvT = 23*M1;           // [256][2048]  ph1-3
  const size_t o_w1b  = 23*M1 + 524288;  // [4][512][2048] ph1-5
  const size_t o_x    = 27*M1 + 524288;  // [4096][2048] ph4-5

  const dim3 tb(256);
  // ---- ph1: conversions (+ weight transposes fused) ----
  cvt4<<<dim3(8192), tb, 0, stream>>>(h,  ws+o_hb,  2097152);
  cvt4<<<dim3(4096), tb, 0, stream>>>(w1, ws+o_w1b, 1048576);
  cvtT<<<dim3(16, 64), tb, 0, stream>>>(wq_comp, ws+o_wqcT, 2048, 512);
  cvtT<<<dim3(64, 16), tb, 0, stream>>>(wq_up,   ws+o_wquT, 512, 2048);
  cvtT<<<dim3(4, 64),  tb, 0, stream>>>(wk, ws+o_wkvT,                     2048, 128);
  cvtT<<<dim3(4, 64),  tb, 0, stream>>>(wv, ws+o_wkvT + (size_t)128*2048,  2048, 128);

  // ---- ph2: qc = h @ wq_comp ; q = qc @ wq_up ; rope+rms (q pre-scaled by 1/(sqrt(D)ln2)) ----
  gemm_bt<false><<<dim3(32, 4),  tb, 0, stream>>>(ws+o_hb, ws+o_wqcT, ws+o_qc, 2048, 2048, 2048, 512, 0, 0, 0);
  gemm_bt<false><<<dim3(32, 16), tb, 0, stream>>>(ws+o_qc, ws+o_wquT, ws+o_qr, 512, 512, 512, 2048, 0, 0, 0);
  rope_rms_kernel<<<dim3(16384), tb, 0, stream>>>(ws+o_qr, ws+o_qr, qnw, 128, 128, 4, 0.12751744f);

  // ---- ph3: kv = h @ [wk|wv] ; rope+rms k -> krt ; transpose v -> vt ----
  gemm_bt<false><<<dim3(32, 2), tb, 0, stream>>>(ws+o_hb, ws+o_wkvT, ws+o_kv, 2048, 2048, 2048, 256, 0, 0, 0);
  rope_rms_kernel<<<dim3(1024), tb, 0, stream>>>(ws+o_kv, ws+o_krt, knw, 256, 128, 0, 1.0f);
  transpose_k<<<dim3(4, 64, 2), tb, 0, stream>>>(ws+o_kv + 128, ws+o_vt, 2048, 128, 256, 2048,
                                                 (long long)2048*256, (long long)128*2048);

  // ---- ph4: attention ----
  attn_kernel<<<dim3(T_/64, H_, B_), tb, 0, stream>>>(ws+o_qr, ws+o_krt, ws+o_vt, sink, ws+o_x);

  // ---- ph5: WeffT = w2T_g @ w1_g^T per group (z=g), then out = x @ WeffT^T ----
  cvtT<<<dim3(64, 256), tb, 0, stream>>>(w2, ws+o_w2T, 8192, 2048);
  gemm_bt<false><<<dim3(16, 4, 4), tb, 0, stream>>>(ws+o_w2T, ws+o_w1b, ws+o_WefT,
                                                    2048, 8192, 2048, 2048,
                                                    2048, (long long)512*2048, 512);
  gemm_bt<true><<<dim3(32, 16), tb, 0, stream>>>(ws+o_x, ws+o_WefT, out,
                                                 2048, 2048, 2048, 2048, 0, 0, 0);
}

// Round 7
// 372.014 us; speedup vs baseline: 5.7889x; 1.2418x over previous
//
#include <hip/hip_runtime.h>
#include <hip/hip_bf16.h>
#include <stdint.h>

typedef __hip_bfloat16 bf16;
typedef __bf16 bf16x8 __attribute__((ext_vector_type(8)));
typedef float f32x4 __attribute__((ext_vector_type(4)));

#define B_ 2
#define T_ 2048
#define HID_ 2048
#define H_ 16
#define D_ 128
#define WIN_ 512

// ---- async global->LDS, 16B per lane (lds dest = wave-uniform base + lane*16) ----
__device__ __forceinline__ void async_copy16(const void* g, void* l) {
  __builtin_amdgcn_global_load_lds(
      (__attribute__((address_space(1))) void*)(uintptr_t)g,
      (__attribute__((address_space(3))) void*)(uint32_t)(uintptr_t)l,
      16, 0, 0);
}

// =================== fp32 -> bf16 conversion, 4 elems/thread ===================
__global__ __launch_bounds__(256) void cvt4(
    const float* __restrict__ in, bf16* __restrict__ out, int n4)
{
  const int i = blockIdx.x * 256 + threadIdx.x;
  if (i >= n4) return;
  const float4 v = ((const float4*)in)[i];
  bf16* p = out + (size_t)i * 4;
  p[0] = __float2bfloat16(v.x);
  p[1] = __float2bfloat16(v.y);
  p[2] = __float2bfloat16(v.z);
  p[3] = __float2bfloat16(v.w);
}

// =================== fused fp32->bf16 + transpose: out[C][R] = bf16(in[R][C]^T) ===================
__global__ __launch_bounds__(256) void cvtT(
    const float* __restrict__ in, bf16* __restrict__ out, int R, int C)
{
  __shared__ bf16 tile[32][33];
  const int bx = blockIdx.x*32, by = blockIdx.y*32;
  const int tx = threadIdx.x & 31, ty = threadIdx.x >> 5;
#pragma unroll
  for (int i = 0; i < 32; i += 8)
    tile[ty+i][tx] = __float2bfloat16(in[(size_t)(by + ty + i)*C + bx + tx]);
  __syncthreads();
#pragma unroll
  for (int i = 0; i < 32; i += 8)
    out[(size_t)(bx + ty + i)*R + by + tx] = tile[tx][ty+i];
}

// =================== bf16 transpose: out[C][R] = in[R][C]^T (batched via z) ===================
__global__ __launch_bounds__(256) void transpose_k(
    const bf16* __restrict__ in, bf16* __restrict__ out,
    int R, int C, int ldin, int ldout, long long inBatch, long long outBatch)
{
  __shared__ bf16 tile[32][33];
  in  += (size_t)blockIdx.z * inBatch;
  out += (size_t)blockIdx.z * outBatch;
  const int bx = blockIdx.x*32, by = blockIdx.y*32;
  const int tx = threadIdx.x & 31, ty = threadIdx.x >> 5;
#pragma unroll
  for (int i = 0; i < 32; i += 8)
    tile[ty+i][tx] = in[(size_t)(by + ty + i)*ldin + bx + tx];
  __syncthreads();
#pragma unroll
  for (int i = 0; i < 32; i += 8)
    out[(size_t)(bx + ty + i)*ldout + by + tx] = tile[tx][ty+i];
}

// =================== bf16 GEMM: C[M,N] = A[M,K] * BT[N,K]^T (m97 + XOR swizzle) ===================
// LDS rows are 64 elems = 8 chunks of 8; chunk c of row r lives at slot c^(r&7).
// Swizzle applied at the GLOBAL source (async dest is fixed); reads XOR with fm&7.
template <bool F32OUT>
__global__ __launch_bounds__(256) void gemm_bt(
    const bf16* __restrict__ Ab, const bf16* __restrict__ Bb, void* __restrict__ Cb,
    int K, int lda, int ldb, int ldc,
    long long sAz, long long sBz, long long sCz)
{
  const bf16* A = Ab + (size_t)blockIdx.z * sAz;
  const bf16* B = Bb + (size_t)blockIdx.z * sBz;
  __shared__ __align__(16) __bf16 sa[128*64];
  __shared__ __align__(16) __bf16 sb[128*64];
  const int bm = blockIdx.x * 128, bn = blockIdx.y * 128;
  const int t = threadIdx.x;
  const int wave = t >> 6, lane = t & 63;
  const int fm = lane & 15, quad = lane >> 4;
  const int wm = (wave & 1) * 64, wn = (wave >> 1) * 64;
  const int arow0 = t >> 3;
  const int acol_sw = (((t & 7) ^ (arow0 & 7)) << 3);   // swizzled source col
  const int fsw = fm & 7;                                // read-side XOR

  f32x4 acc[4][4];
#pragma unroll
  for (int i = 0; i < 4; ++i)
#pragma unroll
    for (int j = 0; j < 4; ++j) acc[i][j] = {0.f, 0.f, 0.f, 0.f};

  for (int k0 = 0; k0 < K; k0 += 64) {
    __syncthreads();
#pragma unroll
    for (int i = 0; i < 4; ++i)
      async_copy16(&A[(size_t)(bm + arow0 + i*32)*lda + k0 + acol_sw], &sa[(size_t)(i*256 + wave*64)*8]);
#pragma unroll
    for (int i = 0; i < 4; ++i)
      async_copy16(&B[(size_t)(bn + arow0 + i*32)*ldb + k0 + acol_sw], &sb[(size_t)(i*256 + wave*64)*8]);
    __syncthreads();
#pragma unroll
    for (int ks = 0; ks < 64; ks += 32) {
      bf16x8 av[4], bv[4];
#pragma unroll
      for (int mt = 0; mt < 4; ++mt)
        av[mt] = *(const bf16x8*)&sa[(wm + mt*16 + fm)*64 + ((((ks>>3) + quad) ^ fsw) << 3)];
#pragma unroll
      for (int nt = 0; nt < 4; ++nt)
        bv[nt] = *(const bf16x8*)&sb[(wn + nt*16 + fm)*64 + ((((ks>>3) + quad) ^ fsw) << 3)];
#pragma unroll
      for (int mt = 0; mt < 4; ++mt)
#pragma unroll
        for (int nt = 0; nt < 4; ++nt)
          acc[mt][nt] = __builtin_amdgcn_mfma_f32_16x16x32_bf16(av[mt], bv[nt], acc[mt][nt], 0, 0, 0);
    }
  }
  if constexpr (F32OUT) {
    float* C = (float*)Cb + (size_t)blockIdx.z * sCz;
#pragma unroll
    for (int mt = 0; mt < 4; ++mt)
#pragma unroll
      for (int r = 0; r < 4; ++r) {
        const int row = bm + wm + mt*16 + quad*4 + r;
#pragma unroll
        for (int nt = 0; nt < 4; ++nt)
          C[(size_t)row*ldc + bn + wn + nt*16 + fm] = acc[mt][nt][r];
      }
  } else {
    bf16* C = (bf16*)Cb + (size_t)blockIdx.z * sCz;
#pragma unroll
    for (int mt = 0; mt < 4; ++mt)
#pragma unroll
      for (int r = 0; r < 4; ++r) {
        const int row = bm + wm + mt*16 + quad*4 + r;
#pragma unroll
        for (int nt = 0; nt < 4; ++nt)
          C[(size_t)row*ldc + bn + wn + nt*16 + fm] = __float2bfloat16(acc[mt][nt][r]);
      }
  }
}

// =================== fused partial-RoPE + RMSNorm (+ output scale), one wave per row ===================
__global__ __launch_bounds__(256) void rope_rms_kernel(
    const bf16* __restrict__ in, bf16* __restrict__ out, const float* __restrict__ w,
    int in_stride, int out_stride, int t_shift, float oscale)
{
  const int rid = blockIdx.x*4 + (threadIdx.x >> 6);
  const int lane = threadIdx.x & 63;
  const bf16* row = in + (size_t)rid * in_stride;
  float e0 = __bfloat162float(row[lane]);
  float e1 = __bfloat162float(row[lane + 64]);
  float s2 = e0*e0 + e1*e1;
#pragma unroll
  for (int off = 32; off; off >>= 1) s2 += __shfl_xor(s2, off);
  const float rms = rsqrtf(s2 * (1.f/128.f) + 1e-6f) * oscale;
  const int tpos = (rid >> t_shift) & (T_ - 1);
  const int i = lane & 31;
  const float inv = expf(-(float)i * 0.28782313662425574f);  // ln(10000)/32
  const float ang = (float)tpos * inv;
  float sn, c;
  sincosf(ang, &sn, &c);
  const float other = __shfl_xor(e0, 32);
  const float r0 = (lane < 32) ? (e0*c - other*sn) : (other*sn + e0*c);
  bf16* orow = out + (size_t)rid * out_stride;
  orow[lane]      = __float2bfloat16(r0 * rms * w[lane]);
  orow[lane + 64] = __float2bfloat16(e1 * rms * w[lane + 64]);
}

// =================== sliding-window flash attention (MQA, sink, max-free, swizzled LDS) ===================
__global__ __launch_bounds__(256) void attn_kernel(
    const bf16* __restrict__ q,     // [B,T,H*D]  (pre-scaled by 1/(sqrt(D)ln2))
    const bf16* __restrict__ k,     // [B,T,D]
    const bf16* __restrict__ vt,    // [B,D,T]
    const float* __restrict__ sink, // [H]
    bf16* __restrict__ o)           // [B,T,H*D]
{
  __shared__ __align__(16) __bf16 sQ[64*128];   // 16 chunk-slots/row, swizzled ^(r&7)
  __shared__ __align__(16) __bf16 sK[64*128];
  __shared__ __align__(16) __bf16 sV[128*64];   // [d][s], 8 slots/row, swizzled ^(d&7)
  __shared__ __align__(16) __bf16 sP[64*72];    // stride 72: 2-way max, no swizzle
  const int qt = blockIdx.x, h = blockIdx.y, b = blockIdx.z;
  const int qb = qt * 64;
  const int t = threadIdx.x, wave = t >> 6, lane = t & 63;
  const int fm = lane & 15, quad = lane >> 4;
  const int fsw = fm & 7;
  const int qw = qb + wave*16;

#pragma unroll
  for (int i = 0; i < 4; ++i) {   // stage Q once (async, source-swizzled)
    int chunk = i*256 + t;
    int r = chunk >> 4, c8 = (chunk & 15) ^ (r & 7);
    async_copy16(&q[(size_t)((b*T_ + qb + r)*H_ + h)*D_ + c8*8], &sQ[(size_t)(i*256 + wave*64)*8]);
  }
  float l_run[4] = {0.f, 0.f, 0.f, 0.f};
  f32x4 oacc[8];
#pragma unroll
  for (int i = 0; i < 8; ++i) oacc[i] = {0.f, 0.f, 0.f, 0.f};

  int lo = qb - (WIN_ - 1); if (lo < 0) lo = 0;
  for (int kt = lo >> 6; kt <= qt; ++kt) {
    const int kb = kt * 64;
    __syncthreads();
#pragma unroll
    for (int i = 0; i < 4; ++i) {   // K tile (source-swizzled)
      int chunk = i*256 + t;
      int r = chunk >> 4, c8 = (chunk & 15) ^ (r & 7);
      async_copy16(&k[(size_t)(b*T_ + kb + r)*D_ + c8*8], &sK[(size_t)(i*256 + wave*64)*8]);
    }
#pragma unroll
    for (int i = 0; i < 4; ++i) {   // V^T tile (source-swizzled)
      int chunk = i*256 + t;
      int d = chunk >> 3, c8 = (chunk & 7) ^ (d & 7);
      async_copy16(&vt[(size_t)(b*D_ + d)*T_ + kb + c8*8], &sV[(size_t)(i*256 + wave*64)*8]);
    }
    __syncthreads();

    // S strip (16 q-rows x 64 k-cols per wave) = Q K^T  (log2-units)
    f32x4 s[4];
#pragma unroll
    for (int nt = 0; nt < 4; ++nt) s[nt] = {0.f, 0.f, 0.f, 0.f};
#pragma unroll
    for (int ds = 0; ds < 4; ++ds) {
      bf16x8 aq = *(const bf16x8*)&sQ[(wave*16 + fm)*128 + (((ds*4 + quad) ^ fsw) << 3)];
#pragma unroll
      for (int nt = 0; nt < 4; ++nt) {
        bf16x8 bk = *(const bf16x8*)&sK[(nt*16 + fm)*128 + (((ds*4 + quad) ^ fsw) << 3)];
        s[nt] = __builtin_amdgcn_mfma_f32_16x16x32_bf16(aq, bk, s[nt], 0, 0, 0);
      }
    }
    const bool interior = (kb + 63 <= qw) && (kb >= qw - (WIN_ - 16));
    if (!interior) {
      const int qi0 = qb + wave*16 + quad*4;
#pragma unroll
      for (int nt = 0; nt < 4; ++nt) {
        const int ki = kb + nt*16 + fm;
#pragma unroll
        for (int r = 0; r < 4; ++r) {
          const int qi = qi0 + r;
          const bool ok = (ki <= qi) && (qi - ki < WIN_);
          s[nt][r] = ok ? s[nt][r] : -1e30f;
        }
      }
    }
#pragma unroll
    for (int nt = 0; nt < 4; ++nt)
#pragma unroll
      for (int r = 0; r < 4; ++r) {
        const float p = __builtin_exp2f(s[nt][r]);
        l_run[r] += p;
        sP[(wave*16 + quad*4 + r)*72 + nt*16 + fm] = __float2bfloat16(p);
      }
    asm volatile("s_waitcnt lgkmcnt(0)" ::: "memory");
    // O += P V
#pragma unroll
    for (int ks = 0; ks < 2; ++ks) {
      bf16x8 ap = *(const bf16x8*)&sP[(wave*16 + fm)*72 + ks*32 + quad*8];
#pragma unroll
      for (int nt = 0; nt < 8; ++nt) {
        bf16x8 bv = *(const bf16x8*)&sV[(nt*16 + fm)*64 + (((ks*4 + quad) ^ fsw) << 3)];
        oacc[nt] = __builtin_amdgcn_mfma_f32_16x16x32_bf16(ap, bv, oacc[nt], 0, 0, 0);
      }
    }
  }
#pragma unroll
  for (int off = 1; off < 16; off <<= 1)
#pragma unroll
    for (int r = 0; r < 4; ++r) l_run[r] += __shfl_xor(l_run[r], off);
  const float sink_p = __builtin_exp2f(sink[h] * 1.4426950408889634f);
#pragma unroll
  for (int r = 0; r < 4; ++r) {
    const int qi = qb + wave*16 + quad*4 + r;
    const float inv_l = 1.f / (l_run[r] + sink_p);
#pragma unroll
    for (int nt = 0; nt < 8; ++nt) {
      const int d = nt*16 + fm;
      o[(size_t)(b*T_ + qi)*(H_*D_) + h*D_ + d] = __float2bfloat16(oacc[nt][r] * inv_l);
    }
  }
}

// =========================================================================================
extern "C" void kernel_launch(void* const* d_in, const int* in_sizes, int n_in,
                              void* d_out, int out_size, void* d_ws, size_t ws_size,
                              hipStream_t stream) {
  (void)in_sizes; (void)n_in; (void)out_size; (void)ws_size;
  const float* h       = (const float*)d_in[0];
  const float* wq_comp = (const float*)d_in[1];
  const float* wq_up   = (const float*)d_in[2];
  const float* wk      = (const float*)d_in[3];
  const float* wv      = (const float*)d_in[4];
  const float* qnw     = (const float*)d_in[5];
  const float* knw     = (const float*)d_in[6];
  const float* sink    = (const float*)d_in[7];
  const float* w1      = (const float*)d_in[8];
  const float* w2      = (const float*)d_in[9];
  float* out = (float*)d_out;
  bf16* ws   = (bf16*)d_ws;

  // ---- overlaid workspace (bf16 element offsets; peak 35.5M elems = 71 MB) ----
  const size_t M1 = 1048576;
  const size_t o_hb    = 0;               // [4096][2048] ph1-3
  const size_t o_qr    = 8*M1;            // [4096][2048] ph2-4
  const size_t o_w2T   = 0;               // [2048][8192] ph5 (hb,qr dead)
  const size_t o_qkv   = 16*M1;           // [4096][768]  ph2-3 (qc|k|v)
  const size_t o_WefT  = 16*M1;           // [2048][2048] ph5 (qkv dead)
  const size_t o_krt   = 20*M1;           // [4096][128]  ph3-4
  const size_t o_vt    = 20*M1 + 524288;  // [2][128][2048] ph3-4
  const size_t o_wqkvT = 21*M1;           // [768][2048]  ph1-3 (wqcT;wkT;wvT stacked)
  const size_t o_wquT  = 22*M1 + 524288;  // [2048][512]  ph1-2
  const size_t o_w1b   = 23*M1 + 524288;  // [4][512][2048] ph1-5
  const size_t o_x     = 27*M1 + 524288;  // [4096][2048] ph4-5

  const dim3 tb(256);
  // ---- ph1: conversions (+ weight transposes fused; qkv weights stacked [768][2048]) ----
  cvt4<<<dim3(8192), tb, 0, stream>>>(h,  ws+o_hb,  2097152);
  cvt4<<<dim3(4096), tb, 0, stream>>>(w1, ws+o_w1b, 1048576);
  cvtT<<<dim3(16, 64), tb, 0, stream>>>(wq_comp, ws+o_wqkvT, 2048, 512);
  cvtT<<<dim3(4, 64),  tb, 0, stream>>>(wk, ws+o_wqkvT + (size_t)512*2048, 2048, 128);
  cvtT<<<dim3(4, 64),  tb, 0, stream>>>(wv, ws+o_wqkvT + (size_t)640*2048, 2048, 128);
  cvtT<<<dim3(64, 16), tb, 0, stream>>>(wq_up, ws+o_wquT, 512, 2048);

  // ---- ph2/3: [qc|k|v] = h @ [wqc|wk|wv] in ONE N=768 GEMM ----
  gemm_bt<false><<<dim3(32, 6), tb, 0, stream>>>(ws+o_hb, ws+o_wqkvT, ws+o_qkv,
                                                 2048, 2048, 2048, 768, 0, 0, 0);
  // q = qc @ wq_up ; rope+rms (q pre-scaled by 1/(sqrt(D)ln2))
  gemm_bt<false><<<dim3(32, 16), tb, 0, stream>>>(ws+o_qkv, ws+o_wquT, ws+o_qr,
                                                  512, 768, 512, 2048, 0, 0, 0);
  rope_rms_kernel<<<dim3(16384), tb, 0, stream>>>(ws+o_qr, ws+o_qr, qnw, 128, 128, 4, 0.12751744f);
  // rope+rms k -> krt ; transpose v -> vt
  rope_rms_kernel<<<dim3(1024), tb, 0, stream>>>(ws+o_qkv + 512, ws+o_krt, knw, 768, 128, 0, 1.0f);
  transpose_k<<<dim3(4, 64, 2), tb, 0, stream>>>(ws+o_qkv + 640, ws+o_vt, 2048, 128, 768, 2048,
                                                 (long long)2048*768, (long long)128*2048);

  // ---- ph4: attention ----
  attn_kernel<<<dim3(T_/64, H_, B_), tb, 0, stream>>>(ws+o_qr, ws+o_krt, ws+o_vt, sink, ws+o_x);

  // ---- ph5: WeffT = w2T_g @ w1_g^T per group (z=g), then out = x @ WeffT^T ----
  cvtT<<<dim3(64, 256), tb, 0, stream>>>(w2, ws+o_w2T, 8192, 2048);
  gemm_bt<false><<<dim3(16, 4, 4), tb, 0, stream>>>(ws+o_w2T, ws+o_w1b, ws+o_WefT,
                                                    2048, 8192, 2048, 2048,
                                                    2048, (long long)512*2048, 512);
  gemm_bt<true><<<dim3(32, 16), tb, 0, stream>>>(ws+o_x, ws+o_WefT, out,
                                                 2048, 2048, 2048, 2048, 0, 0, 0);
}